// Round 12
// baseline (79.676 us; speedup 1.0000x reference)
//
#include <hip/hip_runtime.h>
#include <math.h>

#define IMG_H 768
#define IMG_W 768
#define BATCH 16
#define TH 8                         // output rows per block (full width)
#define TPB 512                      // 8 waves; wave w computes output row y0+w
#define NSTRIPS (IMG_H / TH)         // 96
#define NBLOCKS (NSTRIPS * BATCH)    // 1536  (6 per CU)
#define NPIX ((size_t)BATCH * IMG_H * IMG_W)  // 9437184

typedef const __attribute__((address_space(1))) float* gp1_t;
typedef __attribute__((address_space(3))) float* lp3_t;

__global__ __launch_bounds__(TPB) void sobel_loss_fused(
    const float* __restrict__ vis, const float* __restrict__ ir,
    const float* __restrict__ X, const float* __restrict__ Y,
    float* __restrict__ part, unsigned* __restrict__ counter,
    float* __restrict__ out)
{
    __shared__ __align__(16) float buf[4][TH + 2][IMG_W];   // 122880 B
    __shared__ float red[3][8];
    __shared__ int lastLds;

    const int tid  = threadIdx.x;
    const int lane = tid & 63;
    const int wv   = tid >> 6;
    const int y0   = blockIdx.x * TH;
    const size_t base = (size_t)blockIdx.y * (IMG_H * IMG_W);
    const int bid = blockIdx.y * NSTRIPS + blockIdx.x;

    // ---- stage: wave pair (2k,2k+1) DMAs image k; 15 x 1KB chunks per wave.
    // im = wv>>1 is wave-uniform (no runtime pointer-array indexing).
    {
        const int im = wv >> 1;
        const float* ip = (im == 0) ? vis : (im == 1) ? ir : (im == 2) ? X : Y;
        ip += base;
        const int half = wv & 1;          // even wave: rows 0-4; odd: rows 5-9
        #pragma unroll
        for (int i = 0; i < 15; ++i) {
            const int idx = half * 15 + i;
            const int row = idx / 3, seg = idx % 3;
            int gr = y0 - 1 + row;
            int rc = gr < 0 ? 0 : (gr > IMG_H - 1 ? IMG_H - 1 : gr);  // clamp; OOB zeroed below
            const float* src = ip + (size_t)rc * IMG_W + seg * 256 + lane * 4;
            __builtin_amdgcn_global_load_lds((gp1_t)src, (lp3_t)&buf[im][row][seg * 256], 16, 0, 0);
        }
    }
    __syncthreads();   // drains vmcnt(0) before s_barrier -> all DMA landed

    // zero OOB halo rows (first/last strip only; block-uniform branch)
    if (blockIdx.x == 0) {
        #pragma unroll
        for (int im = 0; im < 4; ++im)
            for (int i = tid; i < IMG_W; i += TPB) buf[im][0][i] = 0.f;
        __syncthreads();
    } else if (blockIdx.x == NSTRIPS - 1) {
        #pragma unroll
        for (int im = 0; im < 4; ++im)
            for (int i = tid; i < IMG_W; i += TPB) buf[im][TH + 1][i] = 0.f;
        __syncthreads();
    }

    // ---- compute: wave wv -> output row y0+wv; lane -> 12 px ----
    const int r0 = wv, r1 = wv + 1, r2 = wv + 2;
    const int xb = lane * 12;        // 48B offset: 16B-aligned

    float jnt[12];
    float sX2 = 0.f, sY2 = 0.f, sL1 = 0.f;

    #pragma unroll
    for (int im = 0; im < 4; ++im) {
        float4 t0 = *(const float4*)&buf[im][r0][xb];
        float4 t1 = *(const float4*)&buf[im][r0][xb + 4];
        float4 t2 = *(const float4*)&buf[im][r0][xb + 8];
        float4 m0 = *(const float4*)&buf[im][r1][xb];
        float4 m1 = *(const float4*)&buf[im][r1][xb + 4];
        float4 m2 = *(const float4*)&buf[im][r1][xb + 8];
        float4 b0 = *(const float4*)&buf[im][r2][xb];
        float4 b1 = *(const float4*)&buf[im][r2][xb + 4];
        float4 b2 = *(const float4*)&buf[im][r2][xb + 8];

        float T[14], M[14], B[14];
        T[1] = t0.x; T[2] = t0.y; T[3] = t0.z; T[4] = t0.w;
        T[5] = t1.x; T[6] = t1.y; T[7] = t1.z; T[8] = t1.w;
        T[9] = t2.x; T[10] = t2.y; T[11] = t2.z; T[12] = t2.w;
        M[1] = m0.x; M[2] = m0.y; M[3] = m0.z; M[4] = m0.w;
        M[5] = m1.x; M[6] = m1.y; M[7] = m1.z; M[8] = m1.w;
        M[9] = m2.x; M[10] = m2.y; M[11] = m2.z; M[12] = m2.w;
        B[1] = b0.x; B[2] = b0.y; B[3] = b0.z; B[4] = b0.w;
        B[5] = b1.x; B[6] = b1.y; B[7] = b1.z; B[8] = b1.w;
        B[9] = b2.x; B[10] = b2.y; B[11] = b2.z; B[12] = b2.w;

        float tl = __shfl_up(t2.w, 1),  tr = __shfl_down(t0.x, 1);
        float ml = __shfl_up(m2.w, 1),  mr = __shfl_down(m0.x, 1);
        float bl = __shfl_up(b2.w, 1),  br = __shfl_down(b0.x, 1);
        T[0] = (lane == 0) ? 0.f : tl;  T[13] = (lane == 63) ? 0.f : tr;
        M[0] = (lane == 0) ? 0.f : ml;  M[13] = (lane == 63) ? 0.f : mr;
        B[0] = (lane == 0) ? 0.f : bl;  B[13] = (lane == 63) ? 0.f : br;

        float s[14], d[14];
        #pragma unroll
        for (int j = 0; j < 14; ++j) { s[j] = T[j] + B[j]; d[j] = T[j] - B[j]; }

        float g[12];
        #pragma unroll
        for (int j = 0; j < 12; ++j) {
            float gx = (s[j + 2] - s[j]) + 2.f * (M[j + 2] - M[j]);
            float gy = d[j] + 2.f * d[j + 1] + d[j + 2];
            g[j] = fabsf(gx) + fabsf(gy);
        }
        if (im == 0) {
            #pragma unroll
            for (int j = 0; j < 12; ++j) jnt[j] = g[j];
        } else if (im == 1) {
            #pragma unroll
            for (int j = 0; j < 12; ++j) jnt[j] = fmaxf(jnt[j], g[j]);
        } else if (im == 2) {
            #pragma unroll
            for (int j = 0; j < 12; ++j) { sX2 += g[j] * g[j]; sL1 += fabsf(g[j] - jnt[j]); }
        } else {
            #pragma unroll
            for (int j = 0; j < 12; ++j) sY2 += g[j] * g[j];
        }
    }

    // ---- block partial reduce ----
    #pragma unroll
    for (int off = 32; off > 0; off >>= 1) {
        sX2 += __shfl_down(sX2, off);
        sY2 += __shfl_down(sY2, off);
        sL1 += __shfl_down(sL1, off);
    }
    if (lane == 0) { red[0][wv] = sX2; red[1][wv] = sY2; red[2][wv] = sL1; }
    __syncthreads();
    if (tid == 0) {
        float a = 0.f, b2 = 0.f, c = 0.f;
        #pragma unroll
        for (int w = 0; w < 8; ++w) { a += red[0][w]; b2 += red[1][w]; c += red[2][w]; }
        part[0 * NBLOCKS + bid] = a;
        part[1 * NBLOCKS + bid] = b2;
        part[2 * NBLOCKS + bid] = c;
        __threadfence();                               // publish partials (device scope)
        unsigned tk = atomicAdd(counter, 1u);
        lastLds = (tk == NBLOCKS - 1);
    }
    __syncthreads();

    // ---- last block finishes: 1536 partials = 3 per thread ----
    if (lastLds) {
        __threadfence();                               // acquire other blocks' stores
        float a = 0.f, b2 = 0.f, c = 0.f;
        #pragma unroll
        for (int k = 0; k < 3; ++k) {
            int i = tid + k * TPB;
            a  += part[0 * NBLOCKS + i];
            b2 += part[1 * NBLOCKS + i];
            c  += part[2 * NBLOCKS + i];
        }
        #pragma unroll
        for (int off = 32; off > 0; off >>= 1) {
            a  += __shfl_down(a,  off);
            b2 += __shfl_down(b2, off);
            c  += __shfl_down(c,  off);
        }
        if (lane == 0) { red[0][wv] = a; red[1][wv] = b2; red[2][wv] = c; }
        __syncthreads();
        if (tid == 0) {
            float sa = 0.f, sb = 0.f, sc = 0.f;
            #pragma unroll
            for (int w = 0; w < 8; ++w) { sa += red[0][w]; sb += red[1][w]; sc += red[2][w]; }
            out[0] = sb / sa;                      // loss_in = sumY2 / sumX2
            out[1] = sc * (1.f / (float)NPIX);     // loss_grad = sumL1 / N
        }
    }
}

extern "C" void kernel_launch(void* const* d_in, const int* in_sizes, int n_in,
                              void* d_out, int out_size, void* d_ws, size_t ws_size,
                              hipStream_t stream) {
    const float* vis = (const float*)d_in[0];
    const float* ir  = (const float*)d_in[1];
    const float* X   = (const float*)d_in[2];
    const float* Y   = (const float*)d_in[3];
    float* out = (float*)d_out;

    unsigned* counter = (unsigned*)d_ws;
    float* part = (float*)((char*)d_ws + 256);   // 3 * NBLOCKS floats

    hipMemsetAsync(counter, 0, sizeof(unsigned), stream);  // ws not re-poisoned between replays
    dim3 grid(NSTRIPS, BATCH);    // 96 x 16 = 1536 blocks
    sobel_loss_fused<<<grid, TPB, 0, stream>>>(vis, ir, X, Y, part, counter, out);
}